// Round 8
// baseline (381.226 us; speedup 1.0000x reference)
//
#include <hip/hip_runtime.h>
#include <hip/hip_bf16.h>
#include <math.h>

#define HIDDEN 256
#define INV_SCALE 0.17677669529663687f  /* 1/sqrt(32) */

typedef __attribute__((ext_vector_type(8))) short short8;
typedef __attribute__((ext_vector_type(4))) float f32x4;
typedef const __attribute__((address_space(1))) unsigned int* gas_ptr;
typedef __attribute__((address_space(3))) unsigned int* las_ptr;

static __device__ __forceinline__ unsigned short f2bf(float x) {
  unsigned u = __float_as_uint(x);
  unsigned r = (u + 0x7FFF + ((u >> 16) & 1)) >> 16;
  return (unsigned short)r;
}
static __device__ __forceinline__ float bf2f(unsigned short u) {
  return __uint_as_float((unsigned)u << 16);
}

#define GLL(gp, lp) __builtin_amdgcn_global_load_lds((gas_ptr)(const void*)(gp), (las_ptr)(void*)(lp), 16, 0, 0)

// ---------------- input / weight conversion to bf16 ----------------

__global__ __launch_bounds__(256) void conv_a_kernel(const float* __restrict__ in,
                                                     unsigned short* __restrict__ out,
                                                     int total4) {
  int stride = gridDim.x * blockDim.x;
  for (int i = blockIdx.x * blockDim.x + threadIdx.x; i < total4; i += stride) {
    float4 f = ((const float4*)in)[i];
    ushort4 u;
    u.x = f2bf(f.x); u.y = f2bf(f.y); u.z = f2bf(f.z); u.w = f2bf(f.w);
    ((ushort4*)out)[i] = u;
  }
}

// Wq,Wk,Wv -> wqkv[768][256], Wo -> wob[256][256]
__global__ __launch_bounds__(256) void conv_w_kernel(const float* __restrict__ Wq,
                                                     const float* __restrict__ Wk,
                                                     const float* __restrict__ Wv,
                                                     const float* __restrict__ Wo,
                                                     unsigned short* __restrict__ wqkv,
                                                     unsigned short* __restrict__ wob) {
  int i = blockIdx.x * 256 + threadIdx.x;  // grid 1024 -> 262144
  int m = i >> 16;
  int j = i & 65535;
  const float* s = (m == 0) ? Wq : (m == 1) ? Wk : (m == 2) ? Wv : Wo;
  unsigned short b = f2bf(s[j]);
  if (m < 3) wqkv[m * 65536 + j] = b;
  else wob[j] = b;
}

// ---------------- CSR build ----------------

__global__ __launch_bounds__(256) void hist_kernel(const int* __restrict__ dst,
                                                   int* __restrict__ deg, int E) {
  int e = blockIdx.x * blockDim.x + threadIdx.x;
  if (e < E) atomicAdd(&deg[dst[e]], 1);
}

__global__ __launch_bounds__(256) void scan1_kernel(const int* __restrict__ deg,
                                                    int* __restrict__ offs,
                                                    int* __restrict__ bsums, int N) {
  __shared__ int s[256];
  int tid = threadIdx.x;
  int base = blockIdx.x * 1024 + tid * 4;
  int v0 = (base + 0 < N) ? deg[base + 0] : 0;
  int v1 = (base + 1 < N) ? deg[base + 1] : 0;
  int v2 = (base + 2 < N) ? deg[base + 2] : 0;
  int v3 = (base + 3 < N) ? deg[base + 3] : 0;
  int tsum = v0 + v1 + v2 + v3;
  s[tid] = tsum;
  __syncthreads();
  for (int off = 1; off < 256; off <<= 1) {
    int t = (tid >= off) ? s[tid - off] : 0;
    __syncthreads();
    s[tid] += t;
    __syncthreads();
  }
  int excl = s[tid] - tsum;
  if (base + 0 < N) offs[base + 0] = excl;
  if (base + 1 < N) offs[base + 1] = excl + v0;
  if (base + 2 < N) offs[base + 2] = excl + v0 + v1;
  if (base + 3 < N) offs[base + 3] = excl + v0 + v1 + v2;
  if (tid == 255) bsums[blockIdx.x] = s[255];
}

__global__ void scan2_kernel(int* __restrict__ bsums, int nb) {
  if (blockIdx.x == 0 && threadIdx.x == 0) {
    int run = 0;
    for (int b = 0; b < nb; ++b) { int t = bsums[b]; bsums[b] = run; run += t; }
  }
}

__global__ __launch_bounds__(256) void scan3_kernel(int* __restrict__ offs,
                                                    int* __restrict__ cursor,
                                                    const int* __restrict__ bsums,
                                                    int N, int E) {
  int i = blockIdx.x * blockDim.x + threadIdx.x;
  if (i < N) {
    int v = offs[i] + bsums[i >> 10];
    offs[i] = v;
    cursor[i] = v;
  }
  if (i == 0) offs[N] = E;
}

__global__ __launch_bounds__(256) void scatter_kernel(const int* __restrict__ dst,
                                                      const int* __restrict__ src,
                                                      int* __restrict__ cursor,
                                                      int* __restrict__ esrc, int E) {
  int e = blockIdx.x * blockDim.x + threadIdx.x;
  if (e < E) {
    int n = dst[e];
    int pos = atomicAdd(&cursor[n], 1);
    esrc[pos] = src[e];
  }
}

// ---------------- A-persistent bf16 MFMA GEMM (1-ahead prefetch, race-free) ----------------
// Block owns 128 rows, ALL of K=256 in registers (af[8][4] short8), loops over
// col-tiles of 128 staging only B half-tiles (4 k-chunks) into parity-dbuf LDS.
// Unit u (parity u&1): stage u+1 -> vmcnt(8) (u done, u+1 in flight) -> barrier ->
// 64 MFMA on parity u -> C-write on odd u -> barrier. Prefetch depth 1 < 2 buffers.
// MODE 0: W=768 cols -> q/k/v bf16 row-major (+bq on q). MODE 1: W=256 -> fp32+bias.
template <int MODE>
__global__ __launch_bounds__(256, 1) void gemm_apersist(const unsigned short* __restrict__ A,
                                                        const unsigned short* __restrict__ B,
                                                        const float* __restrict__ bias,
                                                        float* __restrict__ Cf,
                                                        unsigned short* __restrict__ Cq,
                                                        unsigned short* __restrict__ Ck,
                                                        unsigned short* __restrict__ Cv,
                                                        int M) {
  constexpr int NT = (MODE == 0) ? 6 : 2;  // col-tiles of 128
  constexpr int NU = 2 * NT;               // stage units (half-tile = 4 k-chunks)
  __shared__ unsigned short Bs[2][4][128][32];  // [parity][k-chunk][row][k] 64KB
  int tid = threadIdx.x;
  int lane = tid & 63;
  int wid = tid >> 6;
  int wm = wid >> 1, wn = wid & 1;  // wave tile 64x64
  int brow = blockIdx.x * 128;
  int fr = lane & 15;
  int kg = (lane >> 4) * 8;

  // A fragments for the whole K dimension -> registers (rows padded in ws)
  short8 af[8][4];
#pragma unroll
  for (int kk = 0; kk < 8; ++kk)
#pragma unroll
    for (int mi = 0; mi < 4; ++mi)
      af[kk][mi] = *(const short8*)&A[(size_t)(brow + wm * 64 + mi * 16 + fr) * HIDDEN + kk * 32 + kg];

  // wave wid stages k-chunk wid of a half-tile: Bs[h][wid][r][e] = B[ct*128+r][(h*4+wid)*32+e]
  auto stageB = [&](int u) {
    int ct = u >> 1, h = u & 1;
    const unsigned short* gB = &B[(size_t)(ct * 128 + (lane >> 2)) * HIDDEN + (h * 4 + wid) * 32 + (lane & 3) * 8];
    char* lb = (char*)&Bs[h][wid][0][0];
#pragma unroll
    for (int i = 0; i < 8; ++i)
      GLL(gB + (size_t)(i * 16) * HIDDEN, lb + i * 1024);
  };

  f32x4 acc[4][4];
#pragma unroll
  for (int mi = 0; mi < 4; ++mi)
#pragma unroll
    for (int ni = 0; ni < 4; ++ni) acc[mi][ni] = (f32x4){0.f, 0.f, 0.f, 0.f};

  stageB(0);

#pragma unroll
  for (int u = 0; u < NU; ++u) {
    if (u + 1 < NU) {
      stageB(u + 1);  // opposite parity; its compute finished at previous end-barrier
      asm volatile("s_waitcnt vmcnt(8)" ::: "memory");  // unit u's 8 loads done
    } else {
      asm volatile("s_waitcnt vmcnt(0)" ::: "memory");
    }
    __builtin_amdgcn_s_barrier();
    __builtin_amdgcn_sched_barrier(0);
    int h = u & 1;
#pragma unroll
    for (int kkk = 0; kkk < 4; ++kkk) {
      short8 bf4[4];
#pragma unroll
      for (int ni = 0; ni < 4; ++ni)
        bf4[ni] = *(const short8*)&Bs[h][kkk][wn * 64 + ni * 16 + fr][kg];
#pragma unroll
      for (int mi = 0; mi < 4; ++mi)
#pragma unroll
        for (int ni = 0; ni < 4; ++ni)
          acc[mi][ni] = __builtin_amdgcn_mfma_f32_16x16x32_bf16(af[h * 4 + kkk][mi], bf4[ni], acc[mi][ni], 0, 0, 0);
    }
    if (u & 1) {
      // col-tile (u>>1) complete: write and reset accumulators
      int ct = u >> 1;
      int fq = lane >> 4;
#pragma unroll
      for (int mi = 0; mi < 4; ++mi) {
#pragma unroll
        for (int ni = 0; ni < 4; ++ni) {
          int c = ct * 128 + wn * 64 + ni * 16 + fr;
#pragma unroll
          for (int j = 0; j < 4; ++j) {
            int r = brow + wm * 64 + mi * 16 + fq * 4 + j;
            if (r < M) {
              float val = acc[mi][ni][j];
              if (MODE == 1) {
                Cf[(size_t)r * HIDDEN + c] = val + bias[c];
              } else {
                if (c < 256) Cq[(size_t)r * HIDDEN + c] = f2bf(val + bias[c]);
                else if (c < 512) Ck[(size_t)r * HIDDEN + (c - 256)] = f2bf(val);
                else Cv[(size_t)r * HIDDEN + (c - 512)] = f2bf(val);
              }
            }
          }
          acc[mi][ni] = (f32x4){0.f, 0.f, 0.f, 0.f};
        }
      }
    }
    __builtin_amdgcn_s_barrier();  // all waves done reading Bs[h] before restage
  }
}

// ---------------- per-dst-node attention aggregation (R4 structure) ----------------
// 1 wave per node. lane = 32*half + l; lane owns channels [l*8, l*8+8); head = l>>2.
// halves process edges idx+0 / idx+1 concurrently; combined at the end via shfl_xor(32).
__global__ __launch_bounds__(256) void agg_kernel(const unsigned short* __restrict__ q,
                                                  const unsigned short* __restrict__ k,
                                                  const unsigned short* __restrict__ v,
                                                  const int* __restrict__ offs,
                                                  const int* __restrict__ esrc,
                                                  unsigned short* __restrict__ o, int N) {
  int n = blockIdx.x * 4 + (threadIdx.x >> 6);
  if (n >= N) return;
  int lane = threadIdx.x & 63;
  int half = lane >> 5;
  int l = lane & 31;

  float qf[8];
  {
    ushort4 qa = *(const ushort4*)&q[(size_t)n * HIDDEN + l * 8];
    ushort4 qb = *(const ushort4*)&q[(size_t)n * HIDDEN + l * 8 + 4];
    qf[0] = bf2f(qa.x); qf[1] = bf2f(qa.y); qf[2] = bf2f(qa.z); qf[3] = bf2f(qa.w);
    qf[4] = bf2f(qb.x); qf[5] = bf2f(qb.y); qf[6] = bf2f(qb.z); qf[7] = bf2f(qb.w);
  }

  int e0 = offs[n], e1 = offs[n + 1];
  float wv[8] = {};
  float z = 0.f;

  for (int idx = e0; idx < e1; idx += 2) {
    int my = idx + half;
    bool valid = my < e1;
    int s = esrc[valid ? my : idx];
    const ushort4* kp = (const ushort4*)&k[(size_t)s * HIDDEN + l * 8];
    const ushort4* vp = (const ushort4*)&v[(size_t)s * HIDDEN + l * 8];
    ushort4 ka = kp[0], kb = kp[1];
    ushort4 va = vp[0], vb = vp[1];
    float dot = qf[0] * bf2f(ka.x) + qf[1] * bf2f(ka.y) + qf[2] * bf2f(ka.z) + qf[3] * bf2f(ka.w)
              + qf[4] * bf2f(kb.x) + qf[5] * bf2f(kb.y) + qf[6] * bf2f(kb.z) + qf[7] * bf2f(kb.w);
    dot += __shfl_xor(dot, 1);
    dot += __shfl_xor(dot, 2);   // full 32-ch head dot in all 4 lanes of the group
    float e = 0.f;
    if (valid) e = __expf(fminf(fmaxf(dot * INV_SCALE, -10.f), 10.f));
    wv[0] += e * bf2f(va.x); wv[1] += e * bf2f(va.y);
    wv[2] += e * bf2f(va.z); wv[3] += e * bf2f(va.w);
    wv[4] += e * bf2f(vb.x); wv[5] += e * bf2f(vb.y);
    wv[6] += e * bf2f(vb.z); wv[7] += e * bf2f(vb.w);
    z += e;
  }

  // combine the two halves
#pragma unroll
  for (int j = 0; j < 8; ++j) wv[j] += __shfl_xor(wv[j], 32);
  z += __shfl_xor(z, 32);

  if (half == 0) {
    float inv = 1.0f / z;
    ushort4 o0, o1;
    o0.x = f2bf(wv[0] * inv); o0.y = f2bf(wv[1] * inv);
    o0.z = f2bf(wv[2] * inv); o0.w = f2bf(wv[3] * inv);
    o1.x = f2bf(wv[4] * inv); o1.y = f2bf(wv[5] * inv);
    o1.z = f2bf(wv[6] * inv); o1.w = f2bf(wv[7] * inv);
    ushort4* op = (ushort4*)&o[(size_t)n * HIDDEN + l * 8];
    op[0] = o0; op[1] = o1;
  }
}

// ---------------- launch ----------------

extern "C" void kernel_launch(void* const* d_in, const int* in_sizes, int n_in,
                              void* d_out, int out_size, void* d_ws, size_t ws_size,
                              hipStream_t stream) {
  const float* inputs = (const float*)d_in[0];
  const float* Wq = (const float*)d_in[1];
  const float* bq = (const float*)d_in[2];
  const float* Wk = (const float*)d_in[3];
  const float* Wv = (const float*)d_in[4];
  const float* Wo = (const float*)d_in[5];
  const float* bo = (const float*)d_in[6];
  const int* src = (const int*)d_in[7];
  const int* dst = (const int*)d_in[8];

  int N = in_sizes[0] / HIDDEN;
  int E = in_sizes[7];
  int Mpad = N + 128;  // pad rows so GEMM A-frag overrun stays in allocated ws

  char* w = (char*)d_ws;
  unsigned short* a_bf = (unsigned short*)w; w += (size_t)Mpad * HIDDEN * 2;
  unsigned short* qb = (unsigned short*)w;   w += (size_t)N * HIDDEN * 2;
  unsigned short* kb = (unsigned short*)w;   w += (size_t)N * HIDDEN * 2;
  unsigned short* vb = (unsigned short*)w;   w += (size_t)N * HIDDEN * 2;
  unsigned short* ob = (unsigned short*)w;   w += (size_t)Mpad * HIDDEN * 2;
  unsigned short* wqkv = (unsigned short*)w; w += (size_t)768 * HIDDEN * 2;
  unsigned short* wob = (unsigned short*)w;  w += (size_t)256 * HIDDEN * 2;
  int* deg = (int*)w;    w += (size_t)N * 4;
  int* offs = (int*)w;   w += (size_t)(N + 4) * 4;
  int* cursor = (int*)w; w += (size_t)N * 4;
  int* esrc = (int*)w;   w += (size_t)E * 4;
  int* bsums = (int*)w;  w += 256 * 4;

  // conversions
  conv_a_kernel<<<2048, 256, 0, stream>>>(inputs, a_bf, N * (HIDDEN / 4));
  conv_w_kernel<<<1024, 256, 0, stream>>>(Wq, Wk, Wv, Wo, wqkv, wob);

  // CSR build
  hipMemsetAsync(deg, 0, (size_t)N * 4, stream);
  int eb = (E + 255) / 256;
  hist_kernel<<<eb, 256, 0, stream>>>(dst, deg, E);
  int nb = (N + 1023) / 1024;
  scan1_kernel<<<nb, 256, 0, stream>>>(deg, offs, bsums, N);
  scan2_kernel<<<1, 64, 0, stream>>>(bsums, nb);
  scan3_kernel<<<(N + 255) / 256, 256, 0, stream>>>(offs, cursor, bsums, N, E);
  scatter_kernel<<<eb, 256, 0, stream>>>(dst, src, cursor, esrc, E);

  // fused QKV projection (bf16 MFMA, A-persistent)
  int gblocks = (N + 127) / 128;
  gemm_apersist<0><<<gblocks, 256, 0, stream>>>(a_bf, wqkv, bq, nullptr, qb, kb, vb, N);

  // attention aggregation
  agg_kernel<<<(N + 3) / 4, 256, 0, stream>>>(qb, kb, vb, offs, esrc, ob, N);

  // output projection
  gemm_apersist<1><<<gblocks, 256, 0, stream>>>(ob, wob, bo, (float*)d_out, nullptr, nullptr, nullptr, N);
}

// Round 9
// 338.357 us; speedup vs baseline: 1.1267x; 1.1267x over previous
//
#include <hip/hip_runtime.h>
#include <hip/hip_bf16.h>
#include <math.h>

#define HIDDEN 256
#define INV_SCALE 0.17677669529663687f  /* 1/sqrt(32) */

typedef __attribute__((ext_vector_type(8))) short short8;
typedef __attribute__((ext_vector_type(4))) float f32x4;
typedef const __attribute__((address_space(1))) unsigned int* gas_ptr;
typedef __attribute__((address_space(3))) unsigned int* las_ptr;

static __device__ __forceinline__ unsigned short f2bf(float x) {
  unsigned u = __float_as_uint(x);
  unsigned r = (u + 0x7FFF + ((u >> 16) & 1)) >> 16;
  return (unsigned short)r;
}
static __device__ __forceinline__ float bf2f(unsigned short u) {
  return __uint_as_float((unsigned)u << 16);
}

#define GLL(gp, lp) __builtin_amdgcn_global_load_lds((gas_ptr)(const void*)(gp), (las_ptr)(void*)(lp), 16, 0, 0)

// ---------------- input / weight conversion to bf16 ----------------

__global__ __launch_bounds__(256) void conv_a_kernel(const float* __restrict__ in,
                                                     unsigned short* __restrict__ out,
                                                     int total4) {
  int stride = gridDim.x * blockDim.x;
  for (int i = blockIdx.x * blockDim.x + threadIdx.x; i < total4; i += stride) {
    float4 f = ((const float4*)in)[i];
    ushort4 u;
    u.x = f2bf(f.x); u.y = f2bf(f.y); u.z = f2bf(f.z); u.w = f2bf(f.w);
    ((ushort4*)out)[i] = u;
  }
}

// Wq,Wk,Wv -> wqkv[768][256], Wo -> wob[256][256]
__global__ __launch_bounds__(256) void conv_w_kernel(const float* __restrict__ Wq,
                                                     const float* __restrict__ Wk,
                                                     const float* __restrict__ Wv,
                                                     const float* __restrict__ Wo,
                                                     unsigned short* __restrict__ wqkv,
                                                     unsigned short* __restrict__ wob) {
  int i = blockIdx.x * 256 + threadIdx.x;  // grid 1024 -> 262144
  int m = i >> 16;
  int j = i & 65535;
  const float* s = (m == 0) ? Wq : (m == 1) ? Wk : (m == 2) ? Wv : Wo;
  unsigned short b = f2bf(s[j]);
  if (m < 3) wqkv[m * 65536 + j] = b;
  else wob[j] = b;
}

// ---------------- CSR build ----------------

__global__ __launch_bounds__(256) void hist_kernel(const int* __restrict__ dst,
                                                   int* __restrict__ deg, int E) {
  int e = blockIdx.x * blockDim.x + threadIdx.x;
  if (e < E) atomicAdd(&deg[dst[e]], 1);
}

__global__ __launch_bounds__(256) void scan1_kernel(const int* __restrict__ deg,
                                                    int* __restrict__ offs,
                                                    int* __restrict__ bsums, int N) {
  __shared__ int s[256];
  int tid = threadIdx.x;
  int base = blockIdx.x * 1024 + tid * 4;
  int v0 = (base + 0 < N) ? deg[base + 0] : 0;
  int v1 = (base + 1 < N) ? deg[base + 1] : 0;
  int v2 = (base + 2 < N) ? deg[base + 2] : 0;
  int v3 = (base + 3 < N) ? deg[base + 3] : 0;
  int tsum = v0 + v1 + v2 + v3;
  s[tid] = tsum;
  __syncthreads();
  for (int off = 1; off < 256; off <<= 1) {
    int t = (tid >= off) ? s[tid - off] : 0;
    __syncthreads();
    s[tid] += t;
    __syncthreads();
  }
  int excl = s[tid] - tsum;
  if (base + 0 < N) offs[base + 0] = excl;
  if (base + 1 < N) offs[base + 1] = excl + v0;
  if (base + 2 < N) offs[base + 2] = excl + v0 + v1;
  if (base + 3 < N) offs[base + 3] = excl + v0 + v1 + v2;
  if (tid == 255) bsums[blockIdx.x] = s[255];
}

__global__ void scan2_kernel(int* __restrict__ bsums, int nb) {
  if (blockIdx.x == 0 && threadIdx.x == 0) {
    int run = 0;
    for (int b = 0; b < nb; ++b) { int t = bsums[b]; bsums[b] = run; run += t; }
  }
}

__global__ __launch_bounds__(256) void scan3_kernel(int* __restrict__ offs,
                                                    int* __restrict__ cursor,
                                                    const int* __restrict__ bsums,
                                                    int N, int E) {
  int i = blockIdx.x * blockDim.x + threadIdx.x;
  if (i < N) {
    int v = offs[i] + bsums[i >> 10];
    offs[i] = v;
    cursor[i] = v;
  }
  if (i == 0) offs[N] = E;
}

__global__ __launch_bounds__(256) void scatter_kernel(const int* __restrict__ dst,
                                                      const int* __restrict__ src,
                                                      int* __restrict__ cursor,
                                                      int* __restrict__ esrc, int E) {
  int e = blockIdx.x * blockDim.x + threadIdx.x;
  if (e < E) {
    int n = dst[e];
    int pos = atomicAdd(&cursor[n], 1);
    esrc[pos] = src[e];
  }
}

// ---------------- A-in-LDS bf16 MFMA GEMM ----------------
// Block owns a 128-row stripe. Prologue stages the FULL A stripe (128x256 = 64KB)
// into LDS once (coalesced, R2 pattern). Main loop: flattened units u = ct*8+kk
// over col-tiles ct and k-chunks kk; B k-chunk (8KB) streamed through parity
// dbuf with 1-ahead prefetch + counted vmcnt(2). Compute identical to R2.
// MODE 0: Ncols=768 -> q/k/v bf16 row-major (+bq on q). MODE 1: Ncols=256 -> fp32+bias.
template <int MODE>
__global__ __launch_bounds__(256) void gemm_alds(const unsigned short* __restrict__ A,
                                                 const unsigned short* __restrict__ B,
                                                 const float* __restrict__ bias,
                                                 float* __restrict__ Cf,
                                                 unsigned short* __restrict__ Cq,
                                                 unsigned short* __restrict__ Ck,
                                                 unsigned short* __restrict__ Cv,
                                                 int M) {
  constexpr int NT = (MODE == 0) ? 6 : 2;  // col-tiles of 128
  constexpr int NU = NT * 8;               // units: (ct, k-chunk)
  __shared__ unsigned short As[8][128][32];  // [k-chunk][row][k] 64KB, whole stripe
  __shared__ unsigned short Bs[2][128][32];  // [parity][row][k]   16KB
  int tid = threadIdx.x;
  int lane = tid & 63;
  int wid = tid >> 6;
  int wm = wid >> 1, wn = wid & 1;  // wave tile 64x64
  int brow = blockIdx.x * 128;
  int fr = lane & 15;
  int kg = (lane >> 4) * 8;

  // staging geometry (R2-verified): wave wid covers rows [wid*32,+32), lane -> row wid*32+(lane>>2), k-off (lane&3)*8
  int srow = wid * 32 + (lane >> 2);
  int skoff = (lane & 3) * 8;

  // prologue: stage whole A stripe, chunk kk -> As[kk]
  const unsigned short* gA = &A[(size_t)(brow + srow) * HIDDEN + skoff];
#pragma unroll
  for (int kk = 0; kk < 8; ++kk) {
    char* dA = (char*)&As[kk][0][0] + wid * 2048;
    GLL(gA + kk * 32, dA);
    GLL(gA + kk * 32 + 16 * HIDDEN, dA + 1024);
  }

  // B k-chunk stage: unit u -> ct=u>>3, kk=u&7, parity u&1
  const unsigned short* gBbase = &B[(size_t)srow * HIDDEN + skoff];
  auto stageB = [&](int u) {
    int ct = u >> 3, kk = u & 7;
    const unsigned short* gB = gBbase + (size_t)(ct * 128) * HIDDEN + kk * 32;
    char* dB = (char*)&Bs[u & 1][0][0] + wid * 2048;
    GLL(gB, dB);
    GLL(gB + 16 * HIDDEN, dB + 1024);
  };

  f32x4 acc[4][4];
#pragma unroll
  for (int mi = 0; mi < 4; ++mi)
#pragma unroll
    for (int ni = 0; ni < 4; ++ni) acc[mi][ni] = (f32x4){0.f, 0.f, 0.f, 0.f};

  stageB(0);

  for (int u = 0; u < NU; ++u) {
    int kk = u & 7;
    if (u + 1 < NU) {
      stageB(u + 1);  // opposite parity; its readers finished at previous end-barrier
      asm volatile("s_waitcnt vmcnt(2)" ::: "memory");  // unit u's B (and all A) done
    } else {
      asm volatile("s_waitcnt vmcnt(0)" ::: "memory");
    }
    __builtin_amdgcn_s_barrier();
    __builtin_amdgcn_sched_barrier(0);
    short8 af[4], bf4[4];
#pragma unroll
    for (int mi = 0; mi < 4; ++mi)
      af[mi] = *(const short8*)&As[kk][wm * 64 + mi * 16 + fr][kg];
#pragma unroll
    for (int ni = 0; ni < 4; ++ni)
      bf4[ni] = *(const short8*)&Bs[u & 1][wn * 64 + ni * 16 + fr][kg];
#pragma unroll
    for (int mi = 0; mi < 4; ++mi)
#pragma unroll
      for (int ni = 0; ni < 4; ++ni)
        acc[mi][ni] = __builtin_amdgcn_mfma_f32_16x16x32_bf16(af[mi], bf4[ni], acc[mi][ni], 0, 0, 0);
    if (kk == 7) {
      // col-tile complete: write and reset accumulators
      int ct = u >> 3;
      int fq = lane >> 4;
#pragma unroll
      for (int mi = 0; mi < 4; ++mi) {
#pragma unroll
        for (int ni = 0; ni < 4; ++ni) {
          int c = ct * 128 + wn * 64 + ni * 16 + fr;
#pragma unroll
          for (int j = 0; j < 4; ++j) {
            int r = brow + wm * 64 + mi * 16 + fq * 4 + j;
            if (r < M) {
              float val = acc[mi][ni][j];
              if (MODE == 1) {
                Cf[(size_t)r * HIDDEN + c] = val + bias[c];
              } else {
                if (c < 256) Cq[(size_t)r * HIDDEN + c] = f2bf(val + bias[c]);
                else if (c < 512) Ck[(size_t)r * HIDDEN + (c - 256)] = f2bf(val);
                else Cv[(size_t)r * HIDDEN + (c - 512)] = f2bf(val);
              }
            }
          }
          acc[mi][ni] = (f32x4){0.f, 0.f, 0.f, 0.f};
        }
      }
    }
    __builtin_amdgcn_s_barrier();  // all waves done reading Bs[u&1] before restage
  }
}

// ---------------- per-dst-node attention aggregation (R4 structure) ----------------
// 1 wave per node. lane = 32*half + l; lane owns channels [l*8, l*8+8); head = l>>2.
// halves process edges idx+0 / idx+1 concurrently; combined at the end via shfl_xor(32).
__global__ __launch_bounds__(256) void agg_kernel(const unsigned short* __restrict__ q,
                                                  const unsigned short* __restrict__ k,
                                                  const unsigned short* __restrict__ v,
                                                  const int* __restrict__ offs,
                                                  const int* __restrict__ esrc,
                                                  unsigned short* __restrict__ o, int N) {
  int n = blockIdx.x * 4 + (threadIdx.x >> 6);
  if (n >= N) return;
  int lane = threadIdx.x & 63;
  int half = lane >> 5;
  int l = lane & 31;

  float qf[8];
  {
    ushort4 qa = *(const ushort4*)&q[(size_t)n * HIDDEN + l * 8];
    ushort4 qb = *(const ushort4*)&q[(size_t)n * HIDDEN + l * 8 + 4];
    qf[0] = bf2f(qa.x); qf[1] = bf2f(qa.y); qf[2] = bf2f(qa.z); qf[3] = bf2f(qa.w);
    qf[4] = bf2f(qb.x); qf[5] = bf2f(qb.y); qf[6] = bf2f(qb.z); qf[7] = bf2f(qb.w);
  }

  int e0 = offs[n], e1 = offs[n + 1];
  float wv[8] = {};
  float z = 0.f;

  for (int idx = e0; idx < e1; idx += 2) {
    int my = idx + half;
    bool valid = my < e1;
    int s = esrc[valid ? my : idx];
    const ushort4* kp = (const ushort4*)&k[(size_t)s * HIDDEN + l * 8];
    const ushort4* vp = (const ushort4*)&v[(size_t)s * HIDDEN + l * 8];
    ushort4 ka = kp[0], kb = kp[1];
    ushort4 va = vp[0], vb = vp[1];
    float dot = qf[0] * bf2f(ka.x) + qf[1] * bf2f(ka.y) + qf[2] * bf2f(ka.z) + qf[3] * bf2f(ka.w)
              + qf[4] * bf2f(kb.x) + qf[5] * bf2f(kb.y) + qf[6] * bf2f(kb.z) + qf[7] * bf2f(kb.w);
    dot += __shfl_xor(dot, 1);
    dot += __shfl_xor(dot, 2);   // full 32-ch head dot in all 4 lanes of the group
    float e = 0.f;
    if (valid) e = __expf(fminf(fmaxf(dot * INV_SCALE, -10.f), 10.f));
    wv[0] += e * bf2f(va.x); wv[1] += e * bf2f(va.y);
    wv[2] += e * bf2f(va.z); wv[3] += e * bf2f(va.w);
    wv[4] += e * bf2f(vb.x); wv[5] += e * bf2f(vb.y);
    wv[6] += e * bf2f(vb.z); wv[7] += e * bf2f(vb.w);
    z += e;
  }

  // combine the two halves
#pragma unroll
  for (int j = 0; j < 8; ++j) wv[j] += __shfl_xor(wv[j], 32);
  z += __shfl_xor(z, 32);

  if (half == 0) {
    float inv = 1.0f / z;
    ushort4 o0, o1;
    o0.x = f2bf(wv[0] * inv); o0.y = f2bf(wv[1] * inv);
    o0.z = f2bf(wv[2] * inv); o0.w = f2bf(wv[3] * inv);
    o1.x = f2bf(wv[4] * inv); o1.y = f2bf(wv[5] * inv);
    o1.z = f2bf(wv[6] * inv); o1.w = f2bf(wv[7] * inv);
    ushort4* op = (ushort4*)&o[(size_t)n * HIDDEN + l * 8];
    op[0] = o0; op[1] = o1;
  }
}

// ---------------- launch ----------------

extern "C" void kernel_launch(void* const* d_in, const int* in_sizes, int n_in,
                              void* d_out, int out_size, void* d_ws, size_t ws_size,
                              hipStream_t stream) {
  const float* inputs = (const float*)d_in[0];
  const float* Wq = (const float*)d_in[1];
  const float* bq = (const float*)d_in[2];
  const float* Wk = (const float*)d_in[3];
  const float* Wv = (const float*)d_in[4];
  const float* Wo = (const float*)d_in[5];
  const float* bo = (const float*)d_in[6];
  const int* src = (const int*)d_in[7];
  const int* dst = (const int*)d_in[8];

  int N = in_sizes[0] / HIDDEN;
  int E = in_sizes[7];
  int Mpad = N + 128;  // pad rows so GEMM A-stage overrun stays in allocated ws

  char* w = (char*)d_ws;
  unsigned short* a_bf = (unsigned short*)w; w += (size_t)Mpad * HIDDEN * 2;
  unsigned short* qb = (unsigned short*)w;   w += (size_t)N * HIDDEN * 2;
  unsigned short* kb = (unsigned short*)w;   w += (size_t)N * HIDDEN * 2;
  unsigned short* vb = (unsigned short*)w;   w += (size_t)N * HIDDEN * 2;
  unsigned short* ob = (unsigned short*)w;   w += (size_t)Mpad * HIDDEN * 2;
  unsigned short* wqkv = (unsigned short*)w; w += (size_t)768 * HIDDEN * 2;
  unsigned short* wob = (unsigned short*)w;  w += (size_t)256 * HIDDEN * 2;
  int* deg = (int*)w;    w += (size_t)N * 4;
  int* offs = (int*)w;   w += (size_t)(N + 4) * 4;
  int* cursor = (int*)w; w += (size_t)N * 4;
  int* esrc = (int*)w;   w += (size_t)E * 4;
  int* bsums = (int*)w;  w += 256 * 4;

  // conversions
  conv_a_kernel<<<2048, 256, 0, stream>>>(inputs, a_bf, N * (HIDDEN / 4));
  conv_w_kernel<<<1024, 256, 0, stream>>>(Wq, Wk, Wv, Wo, wqkv, wob);

  // CSR build
  hipMemsetAsync(deg, 0, (size_t)N * 4, stream);
  int eb = (E + 255) / 256;
  hist_kernel<<<eb, 256, 0, stream>>>(dst, deg, E);
  int nb = (N + 1023) / 1024;
  scan1_kernel<<<nb, 256, 0, stream>>>(deg, offs, bsums, N);
  scan2_kernel<<<1, 64, 0, stream>>>(bsums, nb);
  scan3_kernel<<<(N + 255) / 256, 256, 0, stream>>>(offs, cursor, bsums, N, E);
  scatter_kernel<<<eb, 256, 0, stream>>>(dst, src, cursor, esrc, E);

  // fused QKV projection (bf16 MFMA, A-in-LDS)
  int gblocks = (N + 127) / 128;
  gemm_alds<0><<<gblocks, 256, 0, stream>>>(a_bf, wqkv, bq, nullptr, qb, kb, vb, N);

  // attention aggregation
  agg_kernel<<<(N + 3) / 4, 256, 0, stream>>>(qb, kb, vb, offs, esrc, ob, N);

  // output projection
  gemm_alds<1><<<gblocks, 256, 0, stream>>>(ob, wob, bo, (float*)d_out, nullptr, nullptr, nullptr, N);
}